// Round 4
// baseline (616.663 us; speedup 1.0000x reference)
//
#include <hip/hip_runtime.h>
#include <stdint.h>

#define BB 64
#define TT 4096
#define DD 256
#define HH 341
#define HP 384      // padded H: 24 tiles of 16
#define NEGV (-1e9f)

typedef __attribute__((ext_vector_type(8))) short short8;
typedef __attribute__((ext_vector_type(4))) float f32x4;

// ---------------------------------------------------------------- utilities

// A&S 7.1.26 erf (|abs err| <= 1.5e-7) -> exact-GELU substitute.
__device__ inline float gelu_fast(float x) {
  const float y = fabsf(x) * 0.70710678118654752440f;
  const float t = __builtin_amdgcn_rcpf(fmaf(0.3275911f, y, 1.0f));
  float p = fmaf(1.061405429f, t, -1.453152027f);
  p = fmaf(p, t, 1.421413741f);
  p = fmaf(p, t, -0.284496736f);
  p = fmaf(p, t, 0.254829592f);
  p *= t;
  const float e = __expf(-y * y);
  float er = fmaf(-p, e, 1.0f);          // erf(|x|/sqrt(2))
  er = (x < 0.0f) ? -er : er;
  return 0.5f * x * (1.0f + er);
}

__device__ inline uint32_t rotl32(uint32_t x, int d) { return (x << d) | (x >> (32 - d)); }

// JAX threefry2x32, jax_threefry_partitionable=True (verified passing):
// counter = (hi=0, lo=j); key(42) -> (0,42); output = x0 ^ x1.
__device__ inline uint32_t threefry_bits(uint32_t j) {
  const uint32_t K0 = 0u, K1 = 42u;
  const uint32_t K2 = K0 ^ K1 ^ 0x1BD11BDAu;
  uint32_t x0 = 0u, x1 = j;
  x0 += K0; x1 += K1;
#define TF_RND(r) { x0 += x1; x1 = rotl32(x1, r); x1 ^= x0; }
  TF_RND(13) TF_RND(15) TF_RND(26) TF_RND(6)
  x0 += K1; x1 += K2 + 1u;
  TF_RND(17) TF_RND(29) TF_RND(16) TF_RND(24)
  x0 += K2; x1 += K0 + 2u;
  TF_RND(13) TF_RND(15) TF_RND(26) TF_RND(6)
  x0 += K0; x1 += K1 + 3u;
  TF_RND(17) TF_RND(29) TF_RND(16) TF_RND(24)
  x0 += K1; x1 += K2 + 4u;
  TF_RND(13) TF_RND(15) TF_RND(26) TF_RND(6)
  x0 += K2; x1 += K0 + 5u;
#undef TF_RND
  return x0 ^ x1;
}

// round-to-nearest-even fp32 -> bf16 split: x = hi + lo (+ ~2^-17 residual)
__device__ inline void bf16split(float x, short& hi, short& lo) {
  uint32_t u = __float_as_uint(x);
  uint32_t h = (u + 0x7FFFu + ((u >> 16) & 1u)) >> 16;
  float rem = x - __uint_as_float(h << 16);
  uint32_t ur = __float_as_uint(rem);
  uint32_t l = (ur + 0x7FFFu + ((ur >> 16) & 1u)) >> 16;
  hi = (short)h; lo = (short)l;
}

__device__ inline float bred_sum(float v, volatile float* tmp, int tid) {
#pragma unroll
  for (int o = 32; o; o >>= 1) v += __shfl_xor(v, o, 64);
  __syncthreads();
  if ((tid & 63) == 0) tmp[tid >> 6] = v;
  __syncthreads();
  return tmp[0] + tmp[1] + tmp[2] + tmp[3];
}

// joint (sum a, max b) reduce: one barrier pair for both
__device__ inline void bred_summax(float& a, float& b, volatile float* tmp, int tid) {
#pragma unroll
  for (int o = 32; o; o >>= 1) { a += __shfl_xor(a, o, 64); b = fmaxf(b, __shfl_xor(b, o, 64)); }
  __syncthreads();
  if ((tid & 63) == 0) { int w2 = (tid >> 6) * 2; tmp[w2] = a; tmp[w2 + 1] = b; }
  __syncthreads();
  a = tmp[0] + tmp[2] + tmp[4] + tmp[6];
  b = fmaxf(fmaxf(tmp[1], tmp[3]), fmaxf(tmp[5], tmp[7]));
}

// joint (a,b) sum-reduce: one pair of barriers for two values
__device__ inline void bred_sum2(float& a, float& b, volatile float* tmp, int tid) {
#pragma unroll
  for (int o = 32; o; o >>= 1) { a += __shfl_xor(a, o, 64); b += __shfl_xor(b, o, 64); }
  __syncthreads();
  if ((tid & 63) == 0) { int w2 = (tid >> 6) * 2; tmp[w2] = a; tmp[w2 + 1] = b; }
  __syncthreads();
  a = tmp[0] + tmp[2] + tmp[4] + tmp[6];
  b = tmp[1] + tmp[3] + tmp[5] + tmp[7];
}

// joint (a,b,c) int sum-reduce
__device__ inline void bred3_i(int& a, int& b, int& c, volatile int* tmp, int tid) {
#pragma unroll
  for (int o = 32; o; o >>= 1) {
    a += __shfl_xor(a, o, 64);
    b += __shfl_xor(b, o, 64);
    c += __shfl_xor(c, o, 64);
  }
  __syncthreads();
  if ((tid & 63) == 0) { int w3 = (tid >> 6) * 3; tmp[w3] = a; tmp[w3 + 1] = b; tmp[w3 + 2] = c; }
  __syncthreads();
  a = tmp[0] + tmp[3] + tmp[6] + tmp[9];
  b = tmp[1] + tmp[4] + tmp[7] + tmp[10];
  c = tmp[2] + tmp[5] + tmp[8] + tmp[11];
}

// ------------------- kernel 0: transpose + bf16-split W1 -> W1T hi/lo in ws
// W1T layout: [HP][DD] bf16 row-major (h-major, k contiguous); h>=HH rows are 0.
// R4: coalesced READS (thread->h contiguous within W1 row k); the scattered
// stores don't stall. Also zeroes the k2 completion counter each iteration.

__global__ __launch_bounds__(384) void k0_prep(const float* __restrict__ W1,
                                               short* __restrict__ Whi,
                                               short* __restrict__ Wlo,
                                               int* __restrict__ done_ctr) {
  const int k = blockIdx.x;       // 0..255
  const int h = threadIdx.x;      // 0..383
  if (k == 0 && h == 0) *done_ctr = 0;
  float v = (h < HH) ? W1[k * HH + h] : 0.0f;   // consecutive h -> coalesced
  short hi, lo;
  bf16split(v, hi, lo);
  Whi[h * DD + k] = hi;
  Wlo[h * DD + k] = lo;
}

// ------------------- kernel 1: mask+LN+split-bf16 MFMA MLP -> scores
// R4: 32-row tiles, 512 threads (8 waves); each wave owns 3 h-tiles x
// 2 M-tiles. LDS = 32 KB -> 3 blocks/CU = 24 waves/CU (6 waves/SIMD),
// vs 64 KB/2 blocks/16 waves before. TLP hides the per-k0 B-load L2
// latency that the compiler refused to pipeline (VGPR heuristic).
// A (LN'd activations) stored in LDS in MFMA A-fragment order:
// slot(mt,k0,q,i) = mt*512 + k0*64 + q*16 + (i^k0)   (16B units, XOR de-bank)
// holds A[row=mt*16+i][k = k0*32 + q*8 + j], j=0..7.  mt in {0,1}.

__global__ __launch_bounds__(512, 6) void k1_mfma(
    const float* __restrict__ emb, const float* __restrict__ attn,
    const float* __restrict__ gamma, const float* __restrict__ beta,
    const short* __restrict__ Whi, const float* __restrict__ b1,
    const float* __restrict__ W2, const float* __restrict__ b2,
    float* __restrict__ scores) {
  __shared__ short Ahi[8192];   // 16 KB
  __shared__ short Alo[8192];   // 16 KB  (total 32 KB)

  const int bid = blockIdx.x;
  const int b = bid >> 7;             // 128 row-tiles per batch row
  const int t0 = (bid & 127) * 32;
  const int tid = threadIdx.x;
  const int w = tid >> 6;             // wave id 0..7
  const int lane = tid & 63;

  // prefix mask: first row masked -> whole 32-row tile masked
  if (attn[(size_t)b * TT + t0] == 0.0f) {
    if (tid < 32) scores[(size_t)b * TT + t0 + tid] = NEGV;
    return;
  }

  // ---------------- prologue: LN 2 rows per wave-iteration (4 rows/wave)
  {
    const int half = lane >> 5;        // which of the 2 rows
    const int g = lane & 31;           // 8-col group within row
    const int k0g = g >> 2, qg = g & 3;
    float gg[8], bb[8];
#pragma unroll
    for (int j = 0; j < 8; ++j) { gg[j] = gamma[g * 8 + j]; bb[j] = beta[g * 8 + j]; }

    // hoist global loads: one latency round trip
    float a2[2];
    float4 xA2[2], xB2[2];
#pragma unroll
    for (int it = 0; it < 2; ++it) {
      const int il = w * 4 + it * 2 + half;          // local row 0..31
      const size_t rowoff = (size_t)b * TT + t0 + il;
      a2[it] = attn[rowoff];
      const float* ep = emb + rowoff * DD + g * 8;
      xA2[it] = *(const float4*)ep;
      xB2[it] = *(const float4*)(ep + 4);
    }

#pragma unroll
    for (int it = 0; it < 2; ++it) {
      const int il = w * 4 + it * 2 + half;
      const float a = a2[it];
      float x[8];
      x[0] = xA2[it].x * a; x[1] = xA2[it].y * a; x[2] = xA2[it].z * a; x[3] = xA2[it].w * a;
      x[4] = xB2[it].x * a; x[5] = xB2[it].y * a; x[6] = xB2[it].z * a; x[7] = xB2[it].w * a;
      float s = 0.f, ss = 0.f;
#pragma unroll
      for (int j = 0; j < 8; ++j) { s += x[j]; ss += x[j] * x[j]; }
#pragma unroll
      for (int o = 16; o; o >>= 1) { s += __shfl_xor(s, o, 32); ss += __shfl_xor(ss, o, 32); }
      const float mu = s * (1.0f / DD);
      const float rs = 1.0f / sqrtf(ss * (1.0f / DD) - mu * mu + 1e-5f);

      short8 h8, l8;
#pragma unroll
      for (int j = 0; j < 8; ++j) {
        float y = (x[j] - mu) * rs * gg[j] + bb[j];
        short hi, lo;
        bf16split(y, hi, lo);
        h8[j] = hi; l8[j] = lo;
      }
      const int i15 = il & 15, mt = il >> 4;
      const int slot = mt * 512 + k0g * 64 + qg * 16 + (i15 ^ k0g);
      *(short8*)&Ahi[slot * 8] = h8;
      *(short8*)&Alo[slot * 8] = l8;
    }
  }
  __syncthreads();

  // ---------------- K-loop: wave w owns h-tiles {3w .. 3w+2}, 2 M-tiles
  const int r = lane & 15, q = lane >> 4;
  f32x4 acc[3][2];
#pragma unroll
  for (int j = 0; j < 3; ++j)
#pragma unroll
    for (int mt = 0; mt < 2; ++mt) acc[j][mt] = (f32x4){0.f, 0.f, 0.f, 0.f};

  int hb[3];
#pragma unroll
  for (int j = 0; j < 3; ++j) hb[j] = ((w * 3 + j) * 16 + r) * 256 + q * 8;

#pragma unroll
  for (int k0 = 0; k0 < 8; ++k0) {
    short8 ahi[2], alo[2];
#pragma unroll
    for (int mt = 0; mt < 2; ++mt) {
      const int slot = mt * 512 + k0 * 64 + q * 16 + (r ^ k0);
      ahi[mt] = *(const short8*)&Ahi[slot * 8];
      alo[mt] = *(const short8*)&Alo[slot * 8];
    }
#pragma unroll
    for (int j = 0; j < 3; ++j) {
      const short* bp = Whi + hb[j] + k0 * 32;
      short8 bhi = *(const short8*)bp;
      short8 blo = *(const short8*)(bp + HP * DD);   // Wlo follows Whi
#pragma unroll
      for (int mt = 0; mt < 2; ++mt) {
        acc[j][mt] = __builtin_amdgcn_mfma_f32_16x16x32_bf16(ahi[mt], bhi, acc[j][mt], 0, 0, 0);
        acc[j][mt] = __builtin_amdgcn_mfma_f32_16x16x32_bf16(ahi[mt], blo, acc[j][mt], 0, 0, 0);
        acc[j][mt] = __builtin_amdgcn_mfma_f32_16x16x32_bf16(alo[mt], bhi, acc[j][mt], 0, 0, 0);
      }
    }
  }

  // ---------------- epilogue: gelu -> *W2; sum over j per-lane FIRST,
  // then one 4-level shfl reduce per (mt,rr).
  // C/D layout: col(h within tile) = lane&15, row = q*4 + reg  [m89/m91]
  float part[2][4];
#pragma unroll
  for (int mt = 0; mt < 2; ++mt)
#pragma unroll
    for (int rr = 0; rr < 4; ++rr) part[mt][rr] = 0.f;

#pragma unroll
  for (int j = 0; j < 3; ++j) {
    const int h = (w * 3 + j) * 16 + r;
    const float w2v = (h < HH) ? W2[h] : 0.f;
    const float b1v = (h < HH) ? b1[h] : 0.f;
#pragma unroll
    for (int mt = 0; mt < 2; ++mt)
#pragma unroll
      for (int rr = 0; rr < 4; ++rr)
        part[mt][rr] += gelu_fast(acc[j][mt][rr] + b1v) * w2v;
  }

  float sacc[2][4];
#pragma unroll
  for (int mt = 0; mt < 2; ++mt)
#pragma unroll
    for (int rr = 0; rr < 4; ++rr) {
      float v = part[mt][rr];
      v += __shfl_xor(v, 1, 64);
      v += __shfl_xor(v, 2, 64);
      v += __shfl_xor(v, 4, 64);
      v += __shfl_xor(v, 8, 64);
      sacc[mt][rr] = v;
    }

  __syncthreads();                         // all waves done reading A from LDS
  float* sred = (float*)Ahi;               // overlap: 256 floats
  if (r == 0) {
#pragma unroll
    for (int mt = 0; mt < 2; ++mt)
#pragma unroll
      for (int rr = 0; rr < 4; ++rr)
        sred[w * 32 + mt * 16 + q * 4 + rr] = sacc[mt][rr];
  }
  __syncthreads();

  if (tid < 32) {
    float sc = b2[0];
#pragma unroll
    for (int ww = 0; ww < 8; ++ww) sc += sred[ww * 32 + tid];
    float a = attn[(size_t)b * TT + t0 + tid];
    scores[(size_t)b * TT + t0 + tid] = (a != 0.f) ? sc : NEGV;
  }
}

// ---------------- kernel 2: per batch row — entmax15, gumbel top-k, z/g/tv
// Newton for entmax tau (18 rounds, joint f/g reduce); 2-bit radix select
// (16 rounds, joint 3-counter reduce). Proven correct in R2.
// R4: k3 fused via last-block-done pattern with agent-scope atomics
// (counter zeroed by k0 each iteration).

__global__ __launch_bounds__(256) void k2_select(
    const float* __restrict__ attn, float* __restrict__ out,
    float* __restrict__ row_tv, int* __restrict__ done_ctr) {
  __shared__ float gs[TT];
  __shared__ float ftmp[8];
  __shared__ int itmp[12];
  __shared__ int is_last;

  const int b = blockIdx.x, tid = threadIdx.x;
  const float* arow = attn + (size_t)b * TT;
  float* zrow = out + (size_t)b * TT;
  float* grow = out + (size_t)BB * TT + (size_t)b * TT;  // holds scores right now

  float x_loc[16], a_loc[16];
  uint32_t key_loc[16];
  float cnt = 0.0f, mx = -3.4e38f;
#pragma unroll
  for (int i = 0; i < 16; ++i) {
    int t = tid + i * 256;
    float s = grow[t];
    float a = arow[t];
    a_loc[i] = a;
    x_loc[i] = s;
    cnt += a;
    mx = fmaxf(mx, s);
    uint32_t bits = threefry_bits((uint32_t)(b * TT + t));
    float u = __uint_as_float(0x3F800000u | (bits >> 9)) - 1.0f;
    float gum = -logf(1e-6f - logf(u + 1e-6f));
    float pert = (a != 0.0f ? s : 0.0f) + gum;
    uint32_t fb = __float_as_uint(pert);
    uint32_t msk = ((int32_t)fb < 0) ? 0xFFFFFFFFu : 0x80000000u;
    key_loc[i] = fb ^ msk;
  }
  float t_eff = cnt;
  bred_summax(t_eff, mx, ftmp, tid);

#pragma unroll
  for (int i = 0; i < 16; ++i) x_loc[i] = (x_loc[i] - mx) * 0.5f;

  // Newton for tau: f(tau) = sum (x-tau)_+^2, f'(tau) = -2 sum (x-tau)_+
  float tau = -1.0f;
  for (int it = 0; it < 18; ++it) {
    float f = 0.0f, g = 0.0f;
#pragma unroll
    for (int i = 0; i < 16; ++i) {
      float d = x_loc[i] - tau;
      if (d > 0.0f) { f = fmaf(d, d, f); g += d; }
    }
    bred_sum2(f, g, ftmp, tid);
    tau = fminf(tau + (f - 1.0f) / (2.0f * g), -0.015625f);
  }

  float kf = rintf(0.3f * t_eff);
  kf = fminf(fmaxf(kf, 1.0f), fmaxf(t_eff, 1.0f));
  int kk = (int)kf;

  // 2-bit MSD radix select for the k-th largest key
  uint32_t prefix = 0u;
  for (int bit = 30; bit >= 0; bit -= 2) {
    uint32_t ph = (prefix >> 2) >> bit;          // two-step shift: defined at bit=30
    int c1 = 0, c2 = 0, c3 = 0;
#pragma unroll
    for (int i = 0; i < 16; ++i) {
      uint32_t kb = key_loc[i];
      bool m = (((kb >> 2) >> bit) == ph);
      uint32_t d = (kb >> bit) & 3u;
      c1 += (int)(m && d >= 1u);
      c2 += (int)(m && d >= 2u);
      c3 += (int)(m && d == 3u);
    }
    bred3_i(c1, c2, c3, itmp, tid);
    uint32_t dig;
    if (c3 >= kk) dig = 3u;
    else if (c2 >= kk) { dig = 2u; kk -= c3; }
    else if (c1 >= kk) { dig = 1u; kk -= c2; }
    else { dig = 0u; kk -= c1; }
    prefix |= dig << bit;
  }
  const uint32_t thr = prefix;

#pragma unroll
  for (int i = 0; i < 16; ++i) {
    int t = tid + i * 256;
    float d = x_loc[i] - tau;
    float z = (d > 0.0f) ? d * d : 0.0f;
    z *= a_loc[i];
    float h = (key_loc[i] >= thr) ? a_loc[i] : 0.0f;
    float g = (h - z) + z;
    zrow[t] = z;
    gs[t] = g;
  }
  __syncthreads();

  float tvn = 0.0f, tvd = 0.0f;
#pragma unroll
  for (int i = 0; i < 16; ++i) {
    int t = tid + i * 256;
    grow[t] = gs[t];
    if (t > 0) {
      float valid = arow[t] * arow[t - 1];
      tvn += fabsf(gs[t] - gs[t - 1]) * valid;
      tvd += valid;
    }
  }
  tvn = bred_sum(tvn, ftmp, tid);
  tvd = bred_sum(tvd, ftmp, tid);

  // ---- fused finalization: last block to finish reduces row_tv -> reg
  if (tid == 0) {
    __hip_atomic_store(&row_tv[b], tvn / fmaxf(tvd, 1.0f),
                       __ATOMIC_RELEASE, __HIP_MEMORY_SCOPE_AGENT);
    int prev = __hip_atomic_fetch_add(done_ctr, 1,
                                      __ATOMIC_ACQ_REL, __HIP_MEMORY_SCOPE_AGENT);
    is_last = (prev == BB - 1) ? 1 : 0;
  }
  __syncthreads();
  if (is_last && tid < 64) {
    float v = __hip_atomic_load(&row_tv[tid],
                                __ATOMIC_ACQUIRE, __HIP_MEMORY_SCOPE_AGENT);
#pragma unroll
    for (int o = 32; o; o >>= 1) v += __shfl_xor(v, o, 64);
    if (tid == 0) out[2 * BB * TT] = 0.1f * (v * (1.0f / BB));
  }
}

// -------------------------------------------------------------- launcher

extern "C" void kernel_launch(void* const* d_in, const int* in_sizes, int n_in,
                              void* d_out, int out_size, void* d_ws, size_t ws_size,
                              hipStream_t stream) {
  const float* emb   = (const float*)d_in[0];
  const float* attn  = (const float*)d_in[1];
  const float* gamma = (const float*)d_in[2];
  const float* beta  = (const float*)d_in[3];
  const float* W1    = (const float*)d_in[4];
  const float* b1    = (const float*)d_in[5];
  const float* W2    = (const float*)d_in[6];
  const float* b2    = (const float*)d_in[7];
  float* out = (float*)d_out;

  float* row_tv = (float*)d_ws;                        // 64 floats
  int* done_ctr = (int*)((char*)d_ws + 256);           // completion counter
  short* Whi = (short*)((char*)d_ws + 512);            // [HP*DD] bf16 hi
  short* Wlo = Whi + HP * DD;                          // [HP*DD] bf16 lo

  k0_prep<<<dim3(DD), dim3(HP), 0, stream>>>(W1, Whi, Wlo, done_ctr);
  k1_mfma<<<dim3(BB * TT / 32), dim3(512), 0, stream>>>(
      emb, attn, gamma, beta, Whi, b1, W2, b2, out + (size_t)BB * TT);
  k2_select<<<dim3(BB), dim3(256), 0, stream>>>(attn, out, row_tv, done_ctr);
}

// Round 5
// 583.747 us; speedup vs baseline: 1.0564x; 1.0564x over previous
//
#include <hip/hip_runtime.h>
#include <stdint.h>

#define BB 64
#define TT 4096
#define DD 256
#define HH 341
#define HP 384      // padded H: 24 tiles of 16
#define NEGV (-1e9f)

typedef __attribute__((ext_vector_type(8))) short short8;
typedef __attribute__((ext_vector_type(4))) float f32x4;

// ---------------------------------------------------------------- utilities

// A&S 7.1.26 erf (|abs err| <= 1.5e-7) -> exact-GELU substitute.
__device__ inline float gelu_fast(float x) {
  const float y = fabsf(x) * 0.70710678118654752440f;
  const float t = __builtin_amdgcn_rcpf(fmaf(0.3275911f, y, 1.0f));
  float p = fmaf(1.061405429f, t, -1.453152027f);
  p = fmaf(p, t, 1.421413741f);
  p = fmaf(p, t, -0.284496736f);
  p = fmaf(p, t, 0.254829592f);
  p *= t;
  const float e = __expf(-y * y);
  float er = fmaf(-p, e, 1.0f);          // erf(|x|/sqrt(2))
  er = (x < 0.0f) ? -er : er;
  return 0.5f * x * (1.0f + er);
}

__device__ inline uint32_t rotl32(uint32_t x, int d) { return (x << d) | (x >> (32 - d)); }

// JAX threefry2x32, jax_threefry_partitionable=True (verified passing):
// counter = (hi=0, lo=j); key(42) -> (0,42); output = x0 ^ x1.
__device__ inline uint32_t threefry_bits(uint32_t j) {
  const uint32_t K0 = 0u, K1 = 42u;
  const uint32_t K2 = K0 ^ K1 ^ 0x1BD11BDAu;
  uint32_t x0 = 0u, x1 = j;
  x0 += K0; x1 += K1;
#define TF_RND(r) { x0 += x1; x1 = rotl32(x1, r); x1 ^= x0; }
  TF_RND(13) TF_RND(15) TF_RND(26) TF_RND(6)
  x0 += K1; x1 += K2 + 1u;
  TF_RND(17) TF_RND(29) TF_RND(16) TF_RND(24)
  x0 += K2; x1 += K0 + 2u;
  TF_RND(13) TF_RND(15) TF_RND(26) TF_RND(6)
  x0 += K0; x1 += K1 + 3u;
  TF_RND(17) TF_RND(29) TF_RND(16) TF_RND(24)
  x0 += K1; x1 += K2 + 4u;
  TF_RND(13) TF_RND(15) TF_RND(26) TF_RND(6)
  x0 += K2; x1 += K0 + 5u;
#undef TF_RND
  return x0 ^ x1;
}

// round-to-nearest-even fp32 -> bf16 split: x = hi + lo (+ ~2^-17 residual)
__device__ inline void bf16split(float x, short& hi, short& lo) {
  uint32_t u = __float_as_uint(x);
  uint32_t h = (u + 0x7FFFu + ((u >> 16) & 1u)) >> 16;
  float rem = x - __uint_as_float(h << 16);
  uint32_t ur = __float_as_uint(rem);
  uint32_t l = (ur + 0x7FFFu + ((ur >> 16) & 1u)) >> 16;
  hi = (short)h; lo = (short)l;
}

__device__ inline float bred_sum(float v, volatile float* tmp, int tid) {
#pragma unroll
  for (int o = 32; o; o >>= 1) v += __shfl_xor(v, o, 64);
  __syncthreads();
  if ((tid & 63) == 0) tmp[tid >> 6] = v;
  __syncthreads();
  return tmp[0] + tmp[1] + tmp[2] + tmp[3];
}

// joint (sum a, max b) reduce: one barrier pair for both
__device__ inline void bred_summax(float& a, float& b, volatile float* tmp, int tid) {
#pragma unroll
  for (int o = 32; o; o >>= 1) { a += __shfl_xor(a, o, 64); b = fmaxf(b, __shfl_xor(b, o, 64)); }
  __syncthreads();
  if ((tid & 63) == 0) { int w2 = (tid >> 6) * 2; tmp[w2] = a; tmp[w2 + 1] = b; }
  __syncthreads();
  a = tmp[0] + tmp[2] + tmp[4] + tmp[6];
  b = fmaxf(fmaxf(tmp[1], tmp[3]), fmaxf(tmp[5], tmp[7]));
}

// joint (a,b) sum-reduce: one pair of barriers for two values
__device__ inline void bred_sum2(float& a, float& b, volatile float* tmp, int tid) {
#pragma unroll
  for (int o = 32; o; o >>= 1) { a += __shfl_xor(a, o, 64); b += __shfl_xor(b, o, 64); }
  __syncthreads();
  if ((tid & 63) == 0) { int w2 = (tid >> 6) * 2; tmp[w2] = a; tmp[w2 + 1] = b; }
  __syncthreads();
  a = tmp[0] + tmp[2] + tmp[4] + tmp[6];
  b = tmp[1] + tmp[3] + tmp[5] + tmp[7];
}

// joint (a,b,c) int sum-reduce
__device__ inline void bred3_i(int& a, int& b, int& c, volatile int* tmp, int tid) {
#pragma unroll
  for (int o = 32; o; o >>= 1) {
    a += __shfl_xor(a, o, 64);
    b += __shfl_xor(b, o, 64);
    c += __shfl_xor(c, o, 64);
  }
  __syncthreads();
  if ((tid & 63) == 0) { int w3 = (tid >> 6) * 3; tmp[w3] = a; tmp[w3 + 1] = b; tmp[w3 + 2] = c; }
  __syncthreads();
  a = tmp[0] + tmp[3] + tmp[6] + tmp[9];
  b = tmp[1] + tmp[4] + tmp[7] + tmp[10];
  c = tmp[2] + tmp[5] + tmp[8] + tmp[11];
}

// ------------------- kernel 0: transpose + bf16-split W1 -> W1T hi/lo in ws
// W1T layout: [HP][DD] bf16 row-major (h-major, k contiguous); h>=HH rows are 0.
// Coalesced reads; also zeroes the k2 completion counter each iteration.

__global__ __launch_bounds__(384) void k0_prep(const float* __restrict__ W1,
                                               short* __restrict__ Whi,
                                               short* __restrict__ Wlo,
                                               int* __restrict__ done_ctr) {
  const int k = blockIdx.x;       // 0..255
  const int h = threadIdx.x;      // 0..383
  if (k == 0 && h == 0) *done_ctr = 0;
  float v = (h < HH) ? W1[k * HH + h] : 0.0f;   // consecutive h -> coalesced
  short hi, lo;
  bf16split(v, hi, lo);
  Whi[h * DD + k] = hi;
  Wlo[h * DD + k] = lo;
}

// ------------------- kernel 1: mask+LN+split-bf16 MFMA MLP -> scores
// R5: 64-row tiles, 768 threads (12 waves); each wave owns 2 h-tiles x
// 4 M-tiles (acc = 32 AGPR). __launch_bounds__(768,3) -> 170-reg cap gives
// the K-loop room for an EXPLICIT 1-deep B prefetch (R2-R4 diagnosis:
// (512,4)'s 128-cap left ~20 spare regs -> compiler serialized the 6 B
// loads per k0 at full L2 latency each ~ 5K cy/k0 stall).
// A (LN'd activations) stored in LDS in MFMA A-fragment order:
// slot(mt,k0,q,i) = mt*512 + k0*64 + q*16 + (i^k0)   (16B units, XOR de-bank)
// holds A[row=mt*16+i][k = k0*32 + q*8 + j], j=0..7.  mt in {0..3}.

__global__ __launch_bounds__(768, 3) void k1_mfma(
    const float* __restrict__ emb, const float* __restrict__ attn,
    const float* __restrict__ gamma, const float* __restrict__ beta,
    const short* __restrict__ Whi, const float* __restrict__ b1,
    const float* __restrict__ W2, const float* __restrict__ b2,
    float* __restrict__ scores) {
  __shared__ short Ahi[16384];   // 32 KB
  __shared__ short Alo[16384];   // 32 KB  (total 64 KB)

  const int bid = blockIdx.x;
  const int b = bid >> 6;             // 64 row-tiles per batch row
  const int t0 = (bid & 63) * 64;
  const int tid = threadIdx.x;
  const int w = tid >> 6;             // wave id 0..11
  const int lane = tid & 63;

  // prefix mask: first row masked -> whole 64-row tile masked
  if (attn[(size_t)b * TT + t0] == 0.0f) {
    if (tid < 64) scores[(size_t)b * TT + t0 + tid] = NEGV;
    return;
  }

  // ---------------- prologue: LN, 3 guarded passes (2048 row-slots / 768)
  // g = tid&31 is constant across passes; row = it*24 + (tid>>5).
  {
    const int g = tid & 31;            // 8-col group within row
    const int rw = tid >> 5;           // row-slot within pass (0..23)
    const int k0g = g >> 2, qg = g & 3;
    float gg[8], bb[8];
#pragma unroll
    for (int j = 0; j < 8; ++j) { gg[j] = gamma[g * 8 + j]; bb[j] = beta[g * 8 + j]; }

    // hoist all guarded global loads first: one latency round trip
    float a3[3];
    float4 xA3[3], xB3[3];
#pragma unroll
    for (int it = 0; it < 3; ++it) {
      const int row = it * 24 + rw;
      if (row < 64) {
        const size_t rowoff = (size_t)b * TT + t0 + row;
        a3[it] = attn[rowoff];
        const float* ep = emb + rowoff * DD + g * 8;
        xA3[it] = *(const float4*)ep;
        xB3[it] = *(const float4*)(ep + 4);
      }
    }

#pragma unroll
    for (int it = 0; it < 3; ++it) {
      const int row = it * 24 + rw;
      if (row < 64) {
        const float a = a3[it];
        float x[8];
        x[0] = xA3[it].x * a; x[1] = xA3[it].y * a; x[2] = xA3[it].z * a; x[3] = xA3[it].w * a;
        x[4] = xB3[it].x * a; x[5] = xB3[it].y * a; x[6] = xB3[it].z * a; x[7] = xB3[it].w * a;
        float s = 0.f, ss = 0.f;
#pragma unroll
        for (int j = 0; j < 8; ++j) { s += x[j]; ss += x[j] * x[j]; }
#pragma unroll
        for (int o = 16; o; o >>= 1) { s += __shfl_xor(s, o, 32); ss += __shfl_xor(ss, o, 32); }
        const float mu = s * (1.0f / DD);
        const float rs = 1.0f / sqrtf(ss * (1.0f / DD) - mu * mu + 1e-5f);

        short8 h8, l8;
#pragma unroll
        for (int j = 0; j < 8; ++j) {
          float y = (x[j] - mu) * rs * gg[j] + bb[j];
          short hi, lo;
          bf16split(y, hi, lo);
          h8[j] = hi; l8[j] = lo;
        }
        const int i15 = row & 15, mt = row >> 4;
        const int slot = mt * 512 + k0g * 64 + qg * 16 + (i15 ^ k0g);
        *(short8*)&Ahi[slot * 8] = h8;
        *(short8*)&Alo[slot * 8] = l8;
      }
    }
  }
  __syncthreads();

  // ---------------- K-loop: wave w owns h-tiles {2w, 2w+1}, all 4 M-tiles.
  // Explicit 1-deep B prefetch: k0+1's 4 fragments load under k0's MFMAs.
  const int r = lane & 15, q = lane >> 4;
  f32x4 acc[2][4];
#pragma unroll
  for (int j = 0; j < 2; ++j)
#pragma unroll
    for (int mt = 0; mt < 4; ++mt) acc[j][mt] = (f32x4){0.f, 0.f, 0.f, 0.f};

  const int hb0 = ((w * 2 + 0) * 16 + r) * 256 + q * 8;
  const int hb1 = ((w * 2 + 1) * 16 + r) * 256 + q * 8;
  const short* __restrict__ Wlo_ = Whi + HP * DD;   // Wlo follows Whi

  short8 bh0 = *(const short8*)(Whi + hb0);
  short8 bl0 = *(const short8*)(Wlo_ + hb0);
  short8 bh1 = *(const short8*)(Whi + hb1);
  short8 bl1 = *(const short8*)(Wlo_ + hb1);

#pragma unroll
  for (int k0 = 0; k0 < 8; ++k0) {
    short8 nh0, nl0, nh1, nl1;
    if (k0 < 7) {
      const int o = (k0 + 1) * 32;
      nh0 = *(const short8*)(Whi + hb0 + o);
      nl0 = *(const short8*)(Wlo_ + hb0 + o);
      nh1 = *(const short8*)(Whi + hb1 + o);
      nl1 = *(const short8*)(Wlo_ + hb1 + o);
    }
    short8 ahi[4], alo[4];
#pragma unroll
    for (int mt = 0; mt < 4; ++mt) {
      const int slot = mt * 512 + k0 * 64 + q * 16 + (r ^ k0);
      ahi[mt] = *(const short8*)&Ahi[slot * 8];
      alo[mt] = *(const short8*)&Alo[slot * 8];
    }
#pragma unroll
    for (int mt = 0; mt < 4; ++mt) {
      acc[0][mt] = __builtin_amdgcn_mfma_f32_16x16x32_bf16(ahi[mt], bh0, acc[0][mt], 0, 0, 0);
      acc[0][mt] = __builtin_amdgcn_mfma_f32_16x16x32_bf16(ahi[mt], bl0, acc[0][mt], 0, 0, 0);
      acc[0][mt] = __builtin_amdgcn_mfma_f32_16x16x32_bf16(alo[mt], bh0, acc[0][mt], 0, 0, 0);
    }
#pragma unroll
    for (int mt = 0; mt < 4; ++mt) {
      acc[1][mt] = __builtin_amdgcn_mfma_f32_16x16x32_bf16(ahi[mt], bh1, acc[1][mt], 0, 0, 0);
      acc[1][mt] = __builtin_amdgcn_mfma_f32_16x16x32_bf16(ahi[mt], bl1, acc[1][mt], 0, 0, 0);
      acc[1][mt] = __builtin_amdgcn_mfma_f32_16x16x32_bf16(alo[mt], bh1, acc[1][mt], 0, 0, 0);
    }
    if (k0 < 7) { bh0 = nh0; bl0 = nl0; bh1 = nh1; bl1 = nl1; }
  }

  // ---------------- epilogue: gelu -> *W2; sum over j per-lane FIRST,
  // then one 4-level shfl reduce per (mt,rr).
  // C/D layout: col(h within tile) = lane&15, row = q*4 + reg  [m89/m91]
  float part[4][4];
#pragma unroll
  for (int mt = 0; mt < 4; ++mt)
#pragma unroll
    for (int rr = 0; rr < 4; ++rr) part[mt][rr] = 0.f;

#pragma unroll
  for (int j = 0; j < 2; ++j) {
    const int h = (w * 2 + j) * 16 + r;
    const float w2v = (h < HH) ? W2[h] : 0.f;
    const float b1v = (h < HH) ? b1[h] : 0.f;
#pragma unroll
    for (int mt = 0; mt < 4; ++mt)
#pragma unroll
      for (int rr = 0; rr < 4; ++rr)
        part[mt][rr] += gelu_fast(acc[j][mt][rr] + b1v) * w2v;
  }

  float sacc[4][4];
#pragma unroll
  for (int mt = 0; mt < 4; ++mt)
#pragma unroll
    for (int rr = 0; rr < 4; ++rr) {
      float v = part[mt][rr];
      v += __shfl_xor(v, 1, 64);
      v += __shfl_xor(v, 2, 64);
      v += __shfl_xor(v, 4, 64);
      v += __shfl_xor(v, 8, 64);
      sacc[mt][rr] = v;
    }

  __syncthreads();                         // all waves done reading A from LDS
  float* sred = (float*)Ahi;               // overlap: 768 floats
  if (r == 0) {
#pragma unroll
    for (int mt = 0; mt < 4; ++mt)
#pragma unroll
      for (int rr = 0; rr < 4; ++rr)
        sred[w * 64 + mt * 16 + q * 4 + rr] = sacc[mt][rr];
  }
  __syncthreads();

  if (tid < 64) {
    float sc = b2[0];
#pragma unroll
    for (int ww = 0; ww < 12; ++ww) sc += sred[ww * 64 + tid];
    float a = attn[(size_t)b * TT + t0 + tid];
    scores[(size_t)b * TT + t0 + tid] = (a != 0.f) ? sc : NEGV;
  }
}

// ---------------- kernel 2: per batch row — entmax15, gumbel top-k, z/g/tv
// Newton for entmax tau (18 rounds, joint f/g reduce); 2-bit radix select
// (16 rounds, joint 3-counter reduce). k3 fused via last-block-done pattern
// with agent-scope atomics (counter zeroed by k0 each iteration). Proven.

__global__ __launch_bounds__(256) void k2_select(
    const float* __restrict__ attn, float* __restrict__ out,
    float* __restrict__ row_tv, int* __restrict__ done_ctr) {
  __shared__ float gs[TT];
  __shared__ float ftmp[8];
  __shared__ int itmp[12];
  __shared__ int is_last;

  const int b = blockIdx.x, tid = threadIdx.x;
  const float* arow = attn + (size_t)b * TT;
  float* zrow = out + (size_t)b * TT;
  float* grow = out + (size_t)BB * TT + (size_t)b * TT;  // holds scores right now

  float x_loc[16], a_loc[16];
  uint32_t key_loc[16];
  float cnt = 0.0f, mx = -3.4e38f;
#pragma unroll
  for (int i = 0; i < 16; ++i) {
    int t = tid + i * 256;
    float s = grow[t];
    float a = arow[t];
    a_loc[i] = a;
    x_loc[i] = s;
    cnt += a;
    mx = fmaxf(mx, s);
    uint32_t bits = threefry_bits((uint32_t)(b * TT + t));
    float u = __uint_as_float(0x3F800000u | (bits >> 9)) - 1.0f;
    float gum = -logf(1e-6f - logf(u + 1e-6f));
    float pert = (a != 0.0f ? s : 0.0f) + gum;
    uint32_t fb = __float_as_uint(pert);
    uint32_t msk = ((int32_t)fb < 0) ? 0xFFFFFFFFu : 0x80000000u;
    key_loc[i] = fb ^ msk;
  }
  float t_eff = cnt;
  bred_summax(t_eff, mx, ftmp, tid);

#pragma unroll
  for (int i = 0; i < 16; ++i) x_loc[i] = (x_loc[i] - mx) * 0.5f;

  // Newton for tau: f(tau) = sum (x-tau)_+^2, f'(tau) = -2 sum (x-tau)_+
  float tau = -1.0f;
  for (int it = 0; it < 18; ++it) {
    float f = 0.0f, g = 0.0f;
#pragma unroll
    for (int i = 0; i < 16; ++i) {
      float d = x_loc[i] - tau;
      if (d > 0.0f) { f = fmaf(d, d, f); g += d; }
    }
    bred_sum2(f, g, ftmp, tid);
    tau = fminf(tau + (f - 1.0f) / (2.0f * g), -0.015625f);
  }

  float kf = rintf(0.3f * t_eff);
  kf = fminf(fmaxf(kf, 1.0f), fmaxf(t_eff, 1.0f));
  int kk = (int)kf;

  // 2-bit MSD radix select for the k-th largest key
  uint32_t prefix = 0u;
  for (int bit = 30; bit >= 0; bit -= 2) {
    uint32_t ph = (prefix >> 2) >> bit;          // two-step shift: defined at bit=30
    int c1 = 0, c2 = 0, c3 = 0;
#pragma unroll
    for (int i = 0; i < 16; ++i) {
      uint32_t kb = key_loc[i];
      bool m = (((kb >> 2) >> bit) == ph);
      uint32_t d = (kb >> bit) & 3u;
      c1 += (int)(m && d >= 1u);
      c2 += (int)(m && d >= 2u);
      c3 += (int)(m && d == 3u);
    }
    bred3_i(c1, c2, c3, itmp, tid);
    uint32_t dig;
    if (c3 >= kk) dig = 3u;
    else if (c2 >= kk) { dig = 2u; kk -= c3; }
    else if (c1 >= kk) { dig = 1u; kk -= c2; }
    else { dig = 0u; kk -= c1; }
    prefix |= dig << bit;
  }
  const uint32_t thr = prefix;

#pragma unroll
  for (int i = 0; i < 16; ++i) {
    int t = tid + i * 256;
    float d = x_loc[i] - tau;
    float z = (d > 0.0f) ? d * d : 0.0f;
    z *= a_loc[i];
    float h = (key_loc[i] >= thr) ? a_loc[i] : 0.0f;
    float g = (h - z) + z;
    zrow[t] = z;
    gs[t] = g;
  }
  __syncthreads();

  float tvn = 0.0f, tvd = 0.0f;
#pragma unroll
  for (int i = 0; i < 16; ++i) {
    int t = tid + i * 256;
    grow[t] = gs[t];
    if (t > 0) {
      float valid = arow[t] * arow[t - 1];
      tvn += fabsf(gs[t] - gs[t - 1]) * valid;
      tvd += valid;
    }
  }
  tvn = bred_sum(tvn, ftmp, tid);
  tvd = bred_sum(tvd, ftmp, tid);

  // ---- fused finalization: last block to finish reduces row_tv -> reg
  if (tid == 0) {
    __hip_atomic_store(&row_tv[b], tvn / fmaxf(tvd, 1.0f),
                       __ATOMIC_RELEASE, __HIP_MEMORY_SCOPE_AGENT);
    int prev = __hip_atomic_fetch_add(done_ctr, 1,
                                      __ATOMIC_ACQ_REL, __HIP_MEMORY_SCOPE_AGENT);
    is_last = (prev == BB - 1) ? 1 : 0;
  }
  __syncthreads();
  if (is_last && tid < 64) {
    float v = __hip_atomic_load(&row_tv[tid],
                                __ATOMIC_ACQUIRE, __HIP_MEMORY_SCOPE_AGENT);
#pragma unroll
    for (int o = 32; o; o >>= 1) v += __shfl_xor(v, o, 64);
    if (tid == 0) out[2 * BB * TT] = 0.1f * (v * (1.0f / BB));
  }
}

// -------------------------------------------------------------- launcher

extern "C" void kernel_launch(void* const* d_in, const int* in_sizes, int n_in,
                              void* d_out, int out_size, void* d_ws, size_t ws_size,
                              hipStream_t stream) {
  const float* emb   = (const float*)d_in[0];
  const float* attn  = (const float*)d_in[1];
  const float* gamma = (const float*)d_in[2];
  const float* beta  = (const float*)d_in[3];
  const float* W1    = (const float*)d_in[4];
  const float* b1    = (const float*)d_in[5];
  const float* W2    = (const float*)d_in[6];
  const float* b2    = (const float*)d_in[7];
  float* out = (float*)d_out;

  float* row_tv = (float*)d_ws;                        // 64 floats
  int* done_ctr = (int*)((char*)d_ws + 256);           // completion counter
  short* Whi = (short*)((char*)d_ws + 512);            // [HP*DD] bf16 hi
  short* Wlo = Whi + HP * DD;                          // [HP*DD] bf16 lo

  k0_prep<<<dim3(DD), dim3(HP), 0, stream>>>(W1, Whi, Wlo, done_ctr);
  k1_mfma<<<dim3(BB * TT / 64), dim3(768), 0, stream>>>(
      emb, attn, gamma, beta, Whi, b1, W2, b2, out + (size_t)BB * TT);
  k2_select<<<dim3(BB), dim3(256), 0, stream>>>(attn, out, row_tv, done_ctr);
}